// Round 1
// baseline (224.614 us; speedup 1.0000x reference)
//
#include <hip/hip_runtime.h>

static constexpr int N_DIM = 2048;
static constexpr int BB = 32;   // batch tile
static constexpr int BI = 64;   // i tile
static constexpr int BJ = 64;   // j (reduction) tile

// out[b,i] = max_j M[i,j] * x[b,j]
// 256 threads: t -> (tb = t>>4 in 0..15, ti = t&15 in 0..15)
// thread computes b in {tb*2, tb*2+1}, i in {ti*4 .. ti*4+3}  (2x4 micro-tile)
__global__ __launch_bounds__(256, 1)
void tropical_mv(const float* __restrict__ x, const float* __restrict__ M,
                 float* __restrict__ out)
{
    __shared__ float xs[BB][68];      // +4 pad: conflict-free per-b reads
    __shared__ float Ms[BI][BJ];      // XOR-swizzled within rows

    const int t  = threadIdx.x;
    const int tb = t >> 4;
    const int ti = t & 15;

    const int bi_tiles = N_DIM / BI;              // 32
    const int b0 = (blockIdx.x / bi_tiles) * BB;  // batch-tile origin
    const int i0 = (blockIdx.x % bi_tiles) * BI;  // i-tile origin

    float acc[2][4];
#pragma unroll
    for (int o = 0; o < 2; ++o)
#pragma unroll
        for (int k = 0; k < 4; ++k)
            acc[o][k] = -__builtin_inff();

    const int sr = t >> 4;   // staging row 0..15
    const int sj = t & 15;   // staging j-group 0..15

    for (int j0 = 0; j0 < N_DIM; j0 += BJ) {
        __syncthreads();   // WAR: previous compute done before restaging

        // stage x tile: 32 rows x 64 floats (2 passes of 16 rows)
#pragma unroll
        for (int p = 0; p < 2; ++p) {
            const int r = sr + p * 16;
            const float4 v = *(const float4*)(x + (size_t)(b0 + r) * N_DIM + j0 + sj * 4);
            *(float4*)&xs[r][sj * 4] = v;
        }
        // stage M tile: 64 rows x 64 floats (4 passes), swizzle j-group by (row>>2)&7
#pragma unroll
        for (int p = 0; p < 4; ++p) {
            const int r = sr + p * 16;
            const float4 v = *(const float4*)(M + (size_t)(i0 + r) * N_DIM + j0 + sj * 4);
            const int pj = sj ^ ((r >> 2) & 7);
            *(float4*)&Ms[r][pj * 4] = v;
        }
        __syncthreads();

        // compute: 16 j-groups of 4
#pragma unroll
        for (int jg = 0; jg < BJ / 4; ++jg) {
            const float4 xv0 = *(const float4*)&xs[tb * 2 + 0][jg * 4];
            const float4 xv1 = *(const float4*)&xs[tb * 2 + 1][jg * 4];
            const int pj = (jg ^ (ti & 7)) * 4;   // (row>>2)&7 == ti&7 for rows ti*4+k
#pragma unroll
            for (int k = 0; k < 4; ++k) {
                const float4 mv = *(const float4*)&Ms[ti * 4 + k][pj];
                float a0 = acc[0][k], a1 = acc[1][k];
                a0 = fmaxf(fmaxf(a0, mv.x * xv0.x), mv.y * xv0.y);
                a0 = fmaxf(fmaxf(a0, mv.z * xv0.z), mv.w * xv0.w);
                a1 = fmaxf(fmaxf(a1, mv.x * xv1.x), mv.y * xv1.y);
                a1 = fmaxf(fmaxf(a1, mv.z * xv1.z), mv.w * xv1.w);
                acc[0][k] = a0;
                acc[1][k] = a1;
            }
        }
    }

    // epilogue: 2 coalesced float4 stores per thread
#pragma unroll
    for (int o = 0; o < 2; ++o) {
        const float4 v = make_float4(acc[o][0], acc[o][1], acc[o][2], acc[o][3]);
        *(float4*)(out + (size_t)(b0 + tb * 2 + o) * N_DIM + i0 + ti * 4) = v;
    }
}

extern "C" void kernel_launch(void* const* d_in, const int* in_sizes, int n_in,
                              void* d_out, int out_size, void* d_ws, size_t ws_size,
                              hipStream_t stream)
{
    const float* x = (const float*)d_in[0];
    const float* M = (const float*)d_in[1];
    float* out = (float*)d_out;

    const int B = in_sizes[0] / N_DIM;                 // 256
    dim3 grid((unsigned)((B / BB) * (N_DIM / BI)));    // 8 * 32 = 256 blocks
    dim3 block(256);
    hipLaunchKernelGGL(tropical_mv, grid, block, 0, stream, x, M, out);
}